// Round 9
// baseline (200.127 us; speedup 1.0000x reference)
//
#include <hip/hip_runtime.h>
#include <stdint.h>

#define T_LEN 4096
#define C_DIM 1024
#define NH 16
#define CLOG2E 0.18033688011112042f   // 0.125 * log2(e)

typedef uint16_t u16;
typedef __attribute__((ext_vector_type(4))) float f32x4;
typedef __attribute__((ext_vector_type(16))) float f32x16;
typedef __attribute__((ext_vector_type(8))) __bf16 bf16x8;
typedef __attribute__((ext_vector_type(8))) uint16_t u16x8;
typedef __attribute__((ext_vector_type(4))) float fvec4;

static __device__ __forceinline__ u16 f2b(float f) {
  union { float f; uint32_t u; } v; v.f = f;
  uint32_t u = v.u;
  return (u16)((u + 0x7fffu + ((u >> 16) & 1u)) >> 16);
}

// packed fp32->bf16x2 (RNE) — inline asm, no builtin on gfx950
static __device__ __forceinline__ uint32_t cvtpk(float lo, float hi) {
  uint32_t r;
  asm("v_cvt_pk_bf16_f32 %0, %1, %2" : "=v"(r) : "v"(lo), "v"(hi));
  return r;
}

static __device__ __forceinline__ f32x4 mfma16(u16x8 a, u16x8 b, f32x4 c) {
  return __builtin_amdgcn_mfma_f32_16x16x32_bf16(
      __builtin_bit_cast(bf16x8, a), __builtin_bit_cast(bf16x8, b), c, 0, 0, 0);
}

static __device__ __forceinline__ f32x16 mfma32(u16x8 a, u16x8 b, f32x16 c) {
  return __builtin_amdgcn_mfma_f32_32x32x16_bf16(
      __builtin_bit_cast(bf16x8, a), __builtin_bit_cast(bf16x8, b), c, 0, 0, 0);
}

static __device__ __forceinline__ void gload_lds16(const void* g, void* l) {
  __builtin_amdgcn_global_load_lds(
      (const __attribute__((address_space(1))) uint32_t*)g,
      (__attribute__((address_space(3))) uint32_t*)l, 16, 0, 0);
}

// ---------------- fp32 -> bf16 cast (vectorized) ----------------
__global__ void cvt_kernel(const float* __restrict__ in, u16* __restrict__ out, int n8) {
  int i = blockIdx.x * blockDim.x + threadIdx.x;
  if (i >= n8) return;
  const fvec4* p = (const fvec4*)(in + (size_t)i * 8);
  fvec4 a = p[0], b = p[1];
  u16x8 o;
  o[0] = f2b(a[0]); o[1] = f2b(a[1]); o[2] = f2b(a[2]); o[3] = f2b(a[3]);
  o[4] = f2b(b[0]); o[5] = f2b(b[1]); o[6] = f2b(b[2]); o[7] = f2b(b[3]);
  *(u16x8*)(out + (size_t)i * 8) = o;
}

__global__ void wcvt_kernel(const float* __restrict__ w0, const float* __restrict__ w1,
                            const float* __restrict__ w2, const float* __restrict__ w3,
                            u16* __restrict__ o0, u16* __restrict__ o1,
                            u16* __restrict__ o2, u16* __restrict__ o3, int n8) {
  int i = blockIdx.x * blockDim.x + threadIdx.x;
  if (i >= n8) return;
  const int z = blockIdx.y;
  const float* in = (z == 0) ? w0 : (z == 1) ? w1 : (z == 2) ? w2 : w3;
  u16* out = (z == 0) ? o0 : (z == 1) ? o1 : (z == 2) ? o2 : o3;
  const fvec4* p = (const fvec4*)(in + (size_t)i * 8);
  fvec4 a = p[0], b = p[1];
  u16x8 o;
  o[0] = f2b(a[0]); o[1] = f2b(a[1]); o[2] = f2b(a[2]); o[3] = f2b(a[3]);
  o[4] = f2b(b[0]); o[5] = f2b(b[1]); o[6] = f2b(b[2]); o[7] = f2b(b[3]);
  *(u16x8*)(out + (size_t)i * 8) = o;
}

// ---------------- QKV GEMM (m97 structure) ----------------
// z=0: Q head-major, PRE-SCALED by 0.125*log2e (fp32, exact). z=1: K. z=2: V^T [h][d][t].
__global__ __launch_bounds__(256) void gemm_qkv(
    const u16* __restrict__ xb,
    const u16* __restrict__ wqb, const u16* __restrict__ wkb, const u16* __restrict__ wvb,
    const float* __restrict__ bq, const float* __restrict__ bk, const float* __restrict__ bv,
    u16* __restrict__ qh, u16* __restrict__ kh, u16* __restrict__ vt)
{
  __shared__ u16 sA[128 * 32];
  __shared__ u16 sB[128 * 32];
  const int K = C_DIM;
  const int z = blockIdx.z;
  const u16* wb = (z == 0) ? wqb : (z == 1) ? wkb : wvb;
  const float* bias = (z == 0) ? bq : (z == 1) ? bk : bv;
  const int m0 = blockIdx.x * 128;
  const int n0 = blockIdx.y * 128;
  const int tid = threadIdx.x;
  const int lane = tid & 63;
  const int w = tid >> 6;
  const int wm = (w >> 1) * 64;
  const int wn = (w & 1) * 64;
  const int lr = lane & 15;
  const int lk = (lane >> 4) * 8;

  f32x4 acc[4][4];
#pragma unroll
  for (int m = 0; m < 4; ++m)
#pragma unroll
    for (int n = 0; n < 4; ++n) acc[m][n] = (f32x4){0.f, 0.f, 0.f, 0.f};

  const int srow = tid >> 2;
  const int scol = (tid & 3) * 8;
  const u16* gA = xb + (size_t)(m0 + srow) * K + scol;
  const u16* gB = wb + (size_t)(n0 + srow) * K + scol;

  for (int k0 = 0; k0 < K; k0 += 32) {
    gload_lds16(gA + k0,          &sA[tid * 8]);
    gload_lds16(gA + 64 * K + k0, &sA[2048 + tid * 8]);
    gload_lds16(gB + k0,          &sB[tid * 8]);
    gload_lds16(gB + 64 * K + k0, &sB[2048 + tid * 8]);
    __syncthreads();
    u16x8 af[4], bfr[4];
#pragma unroll
    for (int m = 0; m < 4; ++m) af[m]  = *(const u16x8*)&sA[(wm + m * 16 + lr) * 32 + lk];
#pragma unroll
    for (int n = 0; n < 4; ++n) bfr[n] = *(const u16x8*)&sB[(wn + n * 16 + lr) * 32 + lk];
#pragma unroll
    for (int m = 0; m < 4; ++m)
#pragma unroll
      for (int n = 0; n < 4; ++n) acc[m][n] = mfma16(af[m], bfr[n], acc[m][n]);
    __syncthreads();
  }

  const int lg = lane >> 4;
#pragma unroll
  for (int n = 0; n < 4; ++n) {
    const int o = n0 + wn + n * 16 + lr;
    const float bb = bias[o];
    const int h = o >> 6;
    const int d = o & 63;
#pragma unroll
    for (int m = 0; m < 4; ++m) {
      const int tb = m0 + wm + m * 16 + lg * 4;
      if (z == 2) {
        uint2 pk;
        pk.x = cvtpk(acc[m][n][0] + bb, acc[m][n][1] + bb);
        pk.y = cvtpk(acc[m][n][2] + bb, acc[m][n][3] + bb);
        *(uint2*)&vt[(size_t)o * T_LEN + tb] = pk;
      } else if (z == 0) {
#pragma unroll
        for (int r = 0; r < 4; ++r)
          qh[((size_t)h * T_LEN + tb + r) * 64 + d] = f2b((acc[m][n][r] + bb) * CLOG2E);
      } else {
#pragma unroll
        for (int r = 0; r < 4; ++r)
          kh[((size_t)h * T_LEN + tb + r) * 64 + d] = f2b(acc[m][n][r] + bb);
      }
    }
  }
}

// ---------------- output projection ----------------
__global__ __launch_bounds__(256) void gemm_proj(
    const u16* __restrict__ yb, const u16* __restrict__ wpb,
    const float* __restrict__ bp, float* __restrict__ out)
{
  __shared__ u16 sA[128 * 32];
  __shared__ u16 sB[128 * 32];
  const int K = C_DIM;
  const int m0 = blockIdx.x * 128;
  const int n0 = blockIdx.y * 128;
  const int tid = threadIdx.x;
  const int lane = tid & 63;
  const int w = tid >> 6;
  const int wm = (w >> 1) * 64;
  const int wn = (w & 1) * 64;
  const int lr = lane & 15;
  const int lk = (lane >> 4) * 8;

  f32x4 acc[4][4];
#pragma unroll
  for (int m = 0; m < 4; ++m)
#pragma unroll
    for (int n = 0; n < 4; ++n) acc[m][n] = (f32x4){0.f, 0.f, 0.f, 0.f};

  const int srow = tid >> 2;
  const int scol = (tid & 3) * 8;
  const u16* gA = yb  + (size_t)(m0 + srow) * K + scol;
  const u16* gB = wpb + (size_t)(n0 + srow) * K + scol;

  for (int k0 = 0; k0 < K; k0 += 32) {
    gload_lds16(gA + k0,          &sA[tid * 8]);
    gload_lds16(gA + 64 * K + k0, &sA[2048 + tid * 8]);
    gload_lds16(gB + k0,          &sB[tid * 8]);
    gload_lds16(gB + 64 * K + k0, &sB[2048 + tid * 8]);
    __syncthreads();
    u16x8 af[4], bfr[4];
#pragma unroll
    for (int m = 0; m < 4; ++m) af[m]  = *(const u16x8*)&sA[(wm + m * 16 + lr) * 32 + lk];
#pragma unroll
    for (int n = 0; n < 4; ++n) bfr[n] = *(const u16x8*)&sB[(wn + n * 16 + lr) * 32 + lk];
#pragma unroll
    for (int m = 0; m < 4; ++m)
#pragma unroll
      for (int n = 0; n < 4; ++n) acc[m][n] = mfma16(af[m], bfr[n], acc[m][n]);
    __syncthreads();
  }

  const int lg = lane >> 4;
#pragma unroll
  for (int n = 0; n < 4; ++n) {
    const int o = n0 + wn + n * 16 + lr;
    const float bb = bp[o];
#pragma unroll
    for (int m = 0; m < 4; ++m) {
      const int tb = m0 + wm + m * 16 + lg * 4;
#pragma unroll
      for (int r = 0; r < 4; ++r)
        out[(size_t)(tb + r) * C_DIM + o] = acc[m][n][r] + bb;
    }
  }
}

// ---------------- flash attention v9: swapped-QK 32x32, in-register softmax ----
// 128 threads = 2 waves; wave owns 32 q-rows (QBLK=64/block). Grid 1024 (4/CU).
// S^T = K*Q^T via mfma_32x32x16: C/D col=lane&31=q, row=(r&3)+8*(r>>2)+4*hi=kt
// => lane holds 32 of 64 kt for ONE q-row (partner lane^32 holds the rest).
// Softmax fully in-register; P->PV B-frag via cvt_pk + one shfl_xor(32) exchange
// (derivation: dest lane hiD j0-3 <- lane hiS=0 regs [8b+4hiD,+4), j4-7 <- hiS=1
// same regs; lane sends (hi? A: B), keeps the other half).
// K/V reg-staged dbuf + XOR swizzle (R7 barrier structure), XCD-chunked LPT grid.
__global__ __launch_bounds__(128) void attn_kernel(
    const u16* __restrict__ qh, const u16* __restrict__ kh, const u16* __restrict__ vt,
    u16* __restrict__ y)
{
  __shared__ char skb[2][8192];
  __shared__ char svb[2][8192];
  const int bid = blockIdx.x;
  const int j = bid >> 3;
  const int h = ((bid & 7) << 1) + (j & 1);   // 2 heads per XCD chunk
  const int qb = 63 - (j >> 1);               // LPT: longest first
  const int nt = qb + 1;
  const int tid = threadIdx.x;
  const int lane = tid & 63;
  const int wv = tid >> 6;
  const int l31 = lane & 31;
  const int hi = lane >> 5;
  const int swz = (lane & 7) << 4;
  const int qrow = qb * 64 + wv * 32 + l31;   // this lane's q-row

  // staging: 128 threads, 64 rows x 128B per tile; thread owns 64B of row srow
  const int srow = tid >> 1;
  const int scb = (tid & 1) * 64;
  int wo0 = srow * 128 + ((scb +  0) ^ ((srow & 7) << 4));
  int wo1 = srow * 128 + ((scb + 16) ^ ((srow & 7) << 4));
  int wo2 = srow * 128 + ((scb + 32) ^ ((srow & 7) << 4));
  int wo3 = srow * 128 + ((scb + 48) ^ ((srow & 7) << 4));
  const u16* gk = kh + ((size_t)h * T_LEN + srow) * 64 + (tid & 1) * 32;
  const u16* gv = vt + ((size_t)h * 64 + srow) * T_LEN + (tid & 1) * 32;

  // Q fragments (pre-scaled): B-operand, k=d slice: d = dstep*16 + hi*8 + [0..8)
  const u16* qbp = qh + ((size_t)h * T_LEN + qrow) * 64 + hi * 8;
  u16x8 qf0 = *(const u16x8*)(qbp);
  u16x8 qf1 = *(const u16x8*)(qbp + 16);
  u16x8 qf2 = *(const u16x8*)(qbp + 32);
  u16x8 qf3 = *(const u16x8*)(qbp + 48);

  f32x16 oacc0 = {0.f,0.f,0.f,0.f,0.f,0.f,0.f,0.f,0.f,0.f,0.f,0.f,0.f,0.f,0.f,0.f};
  f32x16 oacc1 = oacc0;
  float mrow = -1e30f, lsum = 0.f;

  // prologue: tile 0 into buffer 0
  u16x8 kr0 = *(const u16x8*)(gk +  0), kr1 = *(const u16x8*)(gk +  8);
  u16x8 kr2 = *(const u16x8*)(gk + 16), kr3 = *(const u16x8*)(gk + 24);
  u16x8 vr0 = *(const u16x8*)(gv +  0), vr1 = *(const u16x8*)(gv +  8);
  u16x8 vr2 = *(const u16x8*)(gv + 16), vr3 = *(const u16x8*)(gv + 24);
  *(u16x8*)(skb[0] + wo0) = kr0; *(u16x8*)(skb[0] + wo1) = kr1;
  *(u16x8*)(skb[0] + wo2) = kr2; *(u16x8*)(skb[0] + wo3) = kr3;
  *(u16x8*)(svb[0] + wo0) = vr0; *(u16x8*)(svb[0] + wo1) = vr1;
  *(u16x8*)(svb[0] + wo2) = vr2; *(u16x8*)(svb[0] + wo3) = vr3;
  int cur = 0;

  for (int t = 0; t < nt; ++t) {
    __syncthreads();   // buffer[cur] writes visible
    if (t + 1 < nt) {  // issue next-tile loads (land in regs; written post-compute)
      const size_t ko = (size_t)(t + 1) * 4096;
      kr0 = *(const u16x8*)(gk + ko);      kr1 = *(const u16x8*)(gk + ko + 8);
      kr2 = *(const u16x8*)(gk + ko + 16); kr3 = *(const u16x8*)(gk + ko + 24);
      const int vo = (t + 1) * 64;
      vr0 = *(const u16x8*)(gv + vo);      vr1 = *(const u16x8*)(gv + vo + 8);
      vr2 = *(const u16x8*)(gv + vo + 16); vr3 = *(const u16x8*)(gv + vo + 24);
    }
    const char* skc = skb[cur];
    const char* svc = svb[cur];

    // QK: S^T[kt][q]; s0 = kt block 0-31, s1 = 32-63
    f32x16 s0 = {0.f,0.f,0.f,0.f,0.f,0.f,0.f,0.f,0.f,0.f,0.f,0.f,0.f,0.f,0.f,0.f};
    f32x16 s1 = s0;
    __builtin_amdgcn_s_setprio(1);
#pragma unroll
    for (int d = 0; d < 4; ++d) {
      const int co = (d * 32 + hi * 16) ^ swz;
      u16x8 k0 = *(const u16x8*)(skc + l31 * 128 + co);
      u16x8 k1 = *(const u16x8*)(skc + (32 + l31) * 128 + co);
      u16x8 qf = (d == 0) ? qf0 : (d == 1) ? qf1 : (d == 2) ? qf2 : qf3;
      s0 = mfma32(k0, qf, s0);
      s1 = mfma32(k1, qf, s1);
    }
    __builtin_amdgcn_s_setprio(0);

    // causal mask (diagonal tile only) — kt = kt0 + 32*s + (r&3)+8*(r>>2)+4*hi
    if (t == nt - 1) {
      const int kt0 = t * 64;
#pragma unroll
      for (int r = 0; r < 16; ++r) {
        const int crow = (r & 3) + 8 * (r >> 2) + 4 * hi;
        s0[r] = (kt0 + crow <= qrow) ? s0[r] : -1e30f;
        s1[r] = (kt0 + 32 + crow <= qrow) ? s1[r] : -1e30f;
      }
    }
    // per-lane tile max over this lane's 32 kt values
    float pm = -1e30f;
#pragma unroll
    for (int r = 0; r < 16; ++r) pm = fmaxf(pm, fmaxf(s0[r], s1[r]));

    // defer-max: row max = max(lane, lane^32); vote avoids the shfl on common path
    if (!__all(pm <= mrow)) {
      float pmf = fmaxf(pm, __shfl_xor(pm, 32));
      const float mnew = fmaxf(mrow, pmf);
      const float sc = exp2f(mrow - mnew);
      lsum *= sc;
      oacc0 *= sc;
      oacc1 *= sc;
      mrow = mnew;
    }

    // exp in place; lane-local partial sum
#pragma unroll
    for (int r = 0; r < 16; ++r) {
      s0[r] = exp2f(s0[r] - mrow);
      s1[r] = exp2f(s1[r] - mrow);
      lsum += s0[r] + s1[r];
    }

    // P -> PV B-fragments: pack + one cross-half exchange per ks
    u16x8 pb[4];
#pragma unroll
    for (int ks = 0; ks < 4; ++ks) {
      const int b8 = (ks & 1) * 8;
      float e0, e1, e2, e3, e4, e5, e6, e7;
      if (ks < 2) {
        e0 = s0[b8+0]; e1 = s0[b8+1]; e2 = s0[b8+2]; e3 = s0[b8+3];
        e4 = s0[b8+4]; e5 = s0[b8+5]; e6 = s0[b8+6]; e7 = s0[b8+7];
      } else {
        e0 = s1[b8+0]; e1 = s1[b8+1]; e2 = s1[b8+2]; e3 = s1[b8+3];
        e4 = s1[b8+4]; e5 = s1[b8+5]; e6 = s1[b8+6]; e7 = s1[b8+7];
      }
      uint32_t a0 = cvtpk(e0, e1), a1 = cvtpk(e2, e3);   // regs [8b, 8b+4)
      uint32_t b0 = cvtpk(e4, e5), b1 = cvtpk(e6, e7);   // regs [8b+4, 8b+8)
      uint32_t snd0 = hi ? a0 : b0;
      uint32_t snd1 = hi ? a1 : b1;
      uint32_t rc0 = (uint32_t)__shfl_xor((int)snd0, 32);
      uint32_t rc1 = (uint32_t)__shfl_xor((int)snd1, 32);
      union { uint32_t w[4]; u16x8 v; } pu;
      pu.w[0] = hi ? rc0 : a0;
      pu.w[1] = hi ? rc1 : a1;
      pu.w[2] = hi ? b0 : rc0;
      pu.w[3] = hi ? b1 : rc1;
      pb[ks] = pu.v;
    }

    // PV: O^T[d][q] += V^T * P^T
    __builtin_amdgcn_s_setprio(1);
#pragma unroll
    for (int ks = 0; ks < 4; ++ks) {
      const int co = (ks * 32 + hi * 16) ^ swz;
      u16x8 v0 = *(const u16x8*)(svc + l31 * 128 + co);
      u16x8 v1 = *(const u16x8*)(svc + (32 + l31) * 128 + co);
      oacc0 = mfma32(v0, pb[ks], oacc0);
      oacc1 = mfma32(v1, pb[ks], oacc1);
    }
    __builtin_amdgcn_s_setprio(0);

    if (t + 1 < nt) {   // write prefetched tile into alternate buffer
      char* dk = skb[cur ^ 1];
      char* dv = svb[cur ^ 1];
      *(u16x8*)(dk + wo0) = kr0; *(u16x8*)(dk + wo1) = kr1;
      *(u16x8*)(dk + wo2) = kr2; *(u16x8*)(dk + wo3) = kr3;
      *(u16x8*)(dv + wo0) = vr0; *(u16x8*)(dv + wo1) = vr1;
      *(u16x8*)(dv + wo2) = vr2; *(u16x8*)(dv + wo3) = vr3;
    }
    cur ^= 1;
  }

  // denominator: lane + partner hold complementary halves of the row
  lsum += __shfl_xor(lsum, 32);
  const float inv = 1.0f / lsum;
  u16* yb = y + (size_t)qrow * C_DIM + h * 64;
#pragma unroll
  for (int g = 0; g < 4; ++g) {
    // regs 4g+u <-> rows d = 8g + 4hi + u (consecutive u)
    uint2 p0, p1;
    p0.x = cvtpk(oacc0[4*g+0] * inv, oacc0[4*g+1] * inv);
    p0.y = cvtpk(oacc0[4*g+2] * inv, oacc0[4*g+3] * inv);
    *(uint2*)(yb + 8*g + 4*hi) = p0;
    p1.x = cvtpk(oacc1[4*g+0] * inv, oacc1[4*g+1] * inv);
    p1.y = cvtpk(oacc1[4*g+2] * inv, oacc1[4*g+3] * inv);
    *(uint2*)(yb + 32 + 8*g + 4*hi) = p1;
  }
}

extern "C" void kernel_launch(void* const* d_in, const int* in_sizes, int n_in,
                              void* d_out, int out_size, void* d_ws, size_t ws_size,
                              hipStream_t stream) {
  const float* x  = (const float*)d_in[0];
  const float* wq = (const float*)d_in[1];
  const float* bq = (const float*)d_in[2];
  const float* wk = (const float*)d_in[3];
  const float* bk = (const float*)d_in[4];
  const float* wv = (const float*)d_in[5];
  const float* bv = (const float*)d_in[6];
  const float* wp = (const float*)d_in[7];
  const float* bp = (const float*)d_in[8];

  char* ws = (char*)d_ws;
  const size_t MB = 1024 * 1024;
  u16* xb  = (u16*)(ws + 0 * MB);
  u16* wqb = (u16*)(ws + 8 * MB);
  u16* wkb = (u16*)(ws + 10 * MB);
  u16* wvb = (u16*)(ws + 12 * MB);
  u16* wpb = (u16*)(ws + 14 * MB);
  u16* qh  = (u16*)(ws + 16 * MB);
  u16* kh  = (u16*)(ws + 24 * MB);
  u16* vt  = (u16*)(ws + 32 * MB);
  u16* y   = (u16*)(ws + 40 * MB);

  cvt_kernel<<<dim3(2048), dim3(256), 0, stream>>>(x, xb, 524288);
  wcvt_kernel<<<dim3(512, 4), dim3(256), 0, stream>>>(
      wq, wk, wv, wp, wqb, wkb, wvb, wpb, 131072);

  gemm_qkv<<<dim3(32, 8, 3), dim3(256), 0, stream>>>(
      xb, wqb, wkb, wvb, bq, bk, bv, qh, kh, vt);

  attn_kernel<<<dim3(1024), dim3(128), 0, stream>>>(qh, kh, vt, y);

  gemm_proj<<<dim3(32, 8), dim3(256), 0, stream>>>(y, wpb, bp, (float*)d_out);
}

// Round 10
// 153.255 us; speedup vs baseline: 1.3058x; 1.3058x over previous
//
#include <hip/hip_runtime.h>
#include <stdint.h>

#define T_LEN 4096
#define C_DIM 1024
#define NH 16
#define CLOG2E 0.18033688011112042f   // 0.125 * log2(e)

typedef uint16_t u16;
typedef __attribute__((ext_vector_type(4))) float f32x4;
typedef __attribute__((ext_vector_type(8))) __bf16 bf16x8;
typedef __attribute__((ext_vector_type(8))) uint16_t u16x8;
typedef __attribute__((ext_vector_type(4))) float fvec4;

static __device__ __forceinline__ u16 f2b(float f) {
  union { float f; uint32_t u; } v; v.f = f;
  uint32_t u = v.u;
  return (u16)((u + 0x7fffu + ((u >> 16) & 1u)) >> 16);
}

// packed fp32->bf16x2 (RNE) — inline asm, no builtin on gfx950
static __device__ __forceinline__ uint32_t cvtpk(float lo, float hi) {
  uint32_t r;
  asm("v_cvt_pk_bf16_f32 %0, %1, %2" : "=v"(r) : "v"(lo), "v"(hi));
  return r;
}

static __device__ __forceinline__ f32x4 mfma16(u16x8 a, u16x8 b, f32x4 c) {
  return __builtin_amdgcn_mfma_f32_16x16x32_bf16(
      __builtin_bit_cast(bf16x8, a), __builtin_bit_cast(bf16x8, b), c, 0, 0, 0);
}

static __device__ __forceinline__ void gload_lds16(const void* g, void* l) {
  __builtin_amdgcn_global_load_lds(
      (const __attribute__((address_space(1))) uint32_t*)g,
      (__attribute__((address_space(3))) uint32_t*)l, 16, 0, 0);
}

// ---------------- fp32 -> bf16 cast (vectorized) ----------------
__global__ void cvt_kernel(const float* __restrict__ in, u16* __restrict__ out, int n8) {
  int i = blockIdx.x * blockDim.x + threadIdx.x;
  if (i >= n8) return;
  const fvec4* p = (const fvec4*)(in + (size_t)i * 8);
  fvec4 a = p[0], b = p[1];
  u16x8 o;
  o[0] = f2b(a[0]); o[1] = f2b(a[1]); o[2] = f2b(a[2]); o[3] = f2b(a[3]);
  o[4] = f2b(b[0]); o[5] = f2b(b[1]); o[6] = f2b(b[2]); o[7] = f2b(b[3]);
  *(u16x8*)(out + (size_t)i * 8) = o;
}

__global__ void wcvt_kernel(const float* __restrict__ w0, const float* __restrict__ w1,
                            const float* __restrict__ w2, const float* __restrict__ w3,
                            u16* __restrict__ o0, u16* __restrict__ o1,
                            u16* __restrict__ o2, u16* __restrict__ o3, int n8) {
  int i = blockIdx.x * blockDim.x + threadIdx.x;
  if (i >= n8) return;
  const int z = blockIdx.y;
  const float* in = (z == 0) ? w0 : (z == 1) ? w1 : (z == 2) ? w2 : w3;
  u16* out = (z == 0) ? o0 : (z == 1) ? o1 : (z == 2) ? o2 : o3;
  const fvec4* p = (const fvec4*)(in + (size_t)i * 8);
  fvec4 a = p[0], b = p[1];
  u16x8 o;
  o[0] = f2b(a[0]); o[1] = f2b(a[1]); o[2] = f2b(a[2]); o[3] = f2b(a[3]);
  o[4] = f2b(b[0]); o[5] = f2b(b[1]); o[6] = f2b(b[2]); o[7] = f2b(b[3]);
  *(u16x8*)(out + (size_t)i * 8) = o;
}

// ---------------- QKV GEMM (m97 structure) ----------------
// z=0: Q head-major, PRE-SCALED by 0.125*log2e (fp32, exact). z=1: K. z=2: V^T [h][d][t].
__global__ __launch_bounds__(256) void gemm_qkv(
    const u16* __restrict__ xb,
    const u16* __restrict__ wqb, const u16* __restrict__ wkb, const u16* __restrict__ wvb,
    const float* __restrict__ bq, const float* __restrict__ bk, const float* __restrict__ bv,
    u16* __restrict__ qh, u16* __restrict__ kh, u16* __restrict__ vt)
{
  __shared__ u16 sA[128 * 32];
  __shared__ u16 sB[128 * 32];
  const int K = C_DIM;
  const int z = blockIdx.z;
  const u16* wb = (z == 0) ? wqb : (z == 1) ? wkb : wvb;
  const float* bias = (z == 0) ? bq : (z == 1) ? bk : bv;
  const int m0 = blockIdx.x * 128;
  const int n0 = blockIdx.y * 128;
  const int tid = threadIdx.x;
  const int lane = tid & 63;
  const int w = tid >> 6;
  const int wm = (w >> 1) * 64;
  const int wn = (w & 1) * 64;
  const int lr = lane & 15;
  const int lk = (lane >> 4) * 8;

  f32x4 acc[4][4];
#pragma unroll
  for (int m = 0; m < 4; ++m)
#pragma unroll
    for (int n = 0; n < 4; ++n) acc[m][n] = (f32x4){0.f, 0.f, 0.f, 0.f};

  const int srow = tid >> 2;
  const int scol = (tid & 3) * 8;
  const u16* gA = xb + (size_t)(m0 + srow) * K + scol;
  const u16* gB = wb + (size_t)(n0 + srow) * K + scol;

  for (int k0 = 0; k0 < K; k0 += 32) {
    gload_lds16(gA + k0,          &sA[tid * 8]);
    gload_lds16(gA + 64 * K + k0, &sA[2048 + tid * 8]);
    gload_lds16(gB + k0,          &sB[tid * 8]);
    gload_lds16(gB + 64 * K + k0, &sB[2048 + tid * 8]);
    __syncthreads();
    u16x8 af[4], bfr[4];
#pragma unroll
    for (int m = 0; m < 4; ++m) af[m]  = *(const u16x8*)&sA[(wm + m * 16 + lr) * 32 + lk];
#pragma unroll
    for (int n = 0; n < 4; ++n) bfr[n] = *(const u16x8*)&sB[(wn + n * 16 + lr) * 32 + lk];
#pragma unroll
    for (int m = 0; m < 4; ++m)
#pragma unroll
      for (int n = 0; n < 4; ++n) acc[m][n] = mfma16(af[m], bfr[n], acc[m][n]);
    __syncthreads();
  }

  const int lg = lane >> 4;
#pragma unroll
  for (int n = 0; n < 4; ++n) {
    const int o = n0 + wn + n * 16 + lr;
    const float bb = bias[o];
    const int h = o >> 6;
    const int d = o & 63;
#pragma unroll
    for (int m = 0; m < 4; ++m) {
      const int tb = m0 + wm + m * 16 + lg * 4;
      if (z == 2) {
        uint2 pk;
        pk.x = cvtpk(acc[m][n][0] + bb, acc[m][n][1] + bb);
        pk.y = cvtpk(acc[m][n][2] + bb, acc[m][n][3] + bb);
        *(uint2*)&vt[(size_t)o * T_LEN + tb] = pk;
      } else if (z == 0) {
#pragma unroll
        for (int r = 0; r < 4; ++r)
          qh[((size_t)h * T_LEN + tb + r) * 64 + d] = f2b((acc[m][n][r] + bb) * CLOG2E);
      } else {
#pragma unroll
        for (int r = 0; r < 4; ++r)
          kh[((size_t)h * T_LEN + tb + r) * 64 + d] = f2b(acc[m][n][r] + bb);
      }
    }
  }
}

// ---------------- output projection ----------------
__global__ __launch_bounds__(256) void gemm_proj(
    const u16* __restrict__ yb, const u16* __restrict__ wpb,
    const float* __restrict__ bp, float* __restrict__ out)
{
  __shared__ u16 sA[128 * 32];
  __shared__ u16 sB[128 * 32];
  const int K = C_DIM;
  const int m0 = blockIdx.x * 128;
  const int n0 = blockIdx.y * 128;
  const int tid = threadIdx.x;
  const int lane = tid & 63;
  const int w = tid >> 6;
  const int wm = (w >> 1) * 64;
  const int wn = (w & 1) * 64;
  const int lr = lane & 15;
  const int lk = (lane >> 4) * 8;

  f32x4 acc[4][4];
#pragma unroll
  for (int m = 0; m < 4; ++m)
#pragma unroll
    for (int n = 0; n < 4; ++n) acc[m][n] = (f32x4){0.f, 0.f, 0.f, 0.f};

  const int srow = tid >> 2;
  const int scol = (tid & 3) * 8;
  const u16* gA = yb  + (size_t)(m0 + srow) * K + scol;
  const u16* gB = wpb + (size_t)(n0 + srow) * K + scol;

  for (int k0 = 0; k0 < K; k0 += 32) {
    gload_lds16(gA + k0,          &sA[tid * 8]);
    gload_lds16(gA + 64 * K + k0, &sA[2048 + tid * 8]);
    gload_lds16(gB + k0,          &sB[tid * 8]);
    gload_lds16(gB + 64 * K + k0, &sB[2048 + tid * 8]);
    __syncthreads();
    u16x8 af[4], bfr[4];
#pragma unroll
    for (int m = 0; m < 4; ++m) af[m]  = *(const u16x8*)&sA[(wm + m * 16 + lr) * 32 + lk];
#pragma unroll
    for (int n = 0; n < 4; ++n) bfr[n] = *(const u16x8*)&sB[(wn + n * 16 + lr) * 32 + lk];
#pragma unroll
    for (int m = 0; m < 4; ++m)
#pragma unroll
      for (int n = 0; n < 4; ++n) acc[m][n] = mfma16(af[m], bfr[n], acc[m][n]);
    __syncthreads();
  }

  const int lg = lane >> 4;
#pragma unroll
  for (int n = 0; n < 4; ++n) {
    const int o = n0 + wn + n * 16 + lr;
    const float bb = bp[o];
#pragma unroll
    for (int m = 0; m < 4; ++m) {
      const int tb = m0 + wm + m * 16 + lg * 4;
#pragma unroll
      for (int r = 0; r < 4; ++r)
        out[(size_t)(tb + r) * C_DIM + o] = acc[m][n][r] + bb;
    }
  }
}

// ---------------- flash attention v10 = R7 + swizzled P tile ----------------
// IDENTICAL to R7 (best: 96.7us) except pp pad-72 (9216B) -> linear [4][16][64]
// with XOR swizzle byte^=(lr&7)<<4 on BOTH write and read (rule #21).
// LDS: 41984 -> 40960 B => 4 blocks/CU instead of 3 (the occupancy limiter).
__global__ __launch_bounds__(256) void attn_kernel(
    const u16* __restrict__ qh, const u16* __restrict__ kh, const u16* __restrict__ vt,
    u16* __restrict__ y)
{
  __shared__ char skb[2][8192];
  __shared__ char svb[2][8192];
  __shared__ u16 pp[4][16][64];        // 8192 B, swizzled (was [4][16][72] padded)
  // XCD chunking + LPT: xcd = bid&7 owns heads {2*xcd, 2*xcd+1}; within chunk,
  // j = bid>>3 interleaves heads and descends q-tile length (longest first).
  const int bid = blockIdx.x;
  const int j = bid >> 3;
  const int h = ((bid & 7) << 1) + (j & 1);
  const int qb = 63 - (j >> 1);
  const int nt = qb + 1;
  const int tid = threadIdx.x;
  const int lane = tid & 63;
  const int w = tid >> 6;
  const int lr = lane & 15;
  const int lg = lane >> 4;
  const int sw = (lr & 7) << 4;
  const int qt0 = qb * 64 + w * 16;

  const int srow = tid >> 2;            // 0..63
  const int scb = (tid & 3) * 32;       // byte col within 128B row
  const int wo0 = srow * 128 + (scb ^ ((srow & 7) << 4));
  const int wo1 = srow * 128 + ((scb + 16) ^ ((srow & 7) << 4));
  const u16* gkbase = kh + ((size_t)h * T_LEN + srow) * 64 + (tid & 3) * 16;
  const u16* gvbase = vt + ((size_t)h * 64 + srow) * T_LEN + (tid & 3) * 16;
  char* ppb = (char*)&pp[w][0][0];

  const u16* qbase = qh + ((size_t)h * T_LEN + qt0 + lr) * 64 + lg * 8;
  u16x8 qf0 = *(const u16x8*)(qbase);
  u16x8 qf1 = *(const u16x8*)(qbase + 32);

  f32x4 oacc[4];
#pragma unroll
  for (int i = 0; i < 4; ++i) oacc[i] = (f32x4){0.f, 0.f, 0.f, 0.f};
  float mrow = -1e30f, lsum = 0.f;

  // prologue: tile 0 into buffer 0
  u16x8 ka = *(const u16x8*)(gkbase);
  u16x8 kb = *(const u16x8*)(gkbase + 8);
  u16x8 va = *(const u16x8*)(gvbase);
  u16x8 vb = *(const u16x8*)(gvbase + 8);
  *(u16x8*)(skb[0] + wo0) = ka; *(u16x8*)(skb[0] + wo1) = kb;
  *(u16x8*)(svb[0] + wo0) = va; *(u16x8*)(svb[0] + wo1) = vb;
  int cur = 0;

  for (int t = 0; t < nt; ++t) {
    __syncthreads();   // buffer[cur] writes visible
    if (t + 1 < nt) {  // issue next-tile loads; latency spans this tile's compute
      const size_t ko = (size_t)(t + 1) * 4096;
      ka = *(const u16x8*)(gkbase + ko);
      kb = *(const u16x8*)(gkbase + ko + 8);
      va = *(const u16x8*)(gvbase + (t + 1) * 64);
      vb = *(const u16x8*)(gvbase + (t + 1) * 64 + 8);
    }
    const char* skc = skb[cur];
    const char* svc = svb[cur];

    // S^T = K * Q^T  (scale already folded into Q)
    f32x4 sacc[4];
    __builtin_amdgcn_s_setprio(1);
#pragma unroll
    for (int i = 0; i < 4; ++i) {
      const int ro = (i * 16 + lr) * 128;
      u16x8 a0 = *(const u16x8*)(skc + ro + ((lg * 16) ^ sw));
      u16x8 a1 = *(const u16x8*)(skc + ro + ((lg * 16 + 64) ^ sw));
      f32x4 zz = (f32x4){0.f, 0.f, 0.f, 0.f};
      zz = mfma16(a0, qf0, zz);
      zz = mfma16(a1, qf1, zz);
      sacc[i] = zz;
    }
    __builtin_amdgcn_s_setprio(0);

    float pvv[4][4];
    float pm = -1e30f;                 // PER-LANE tile max (no reduce on common path)
    if (t == nt - 1) {                 // diagonal tile: causal mask
      const int qg = qt0 + lr;
      const int kt0 = t * 64;
#pragma unroll
      for (int i = 0; i < 4; ++i) {
#pragma unroll
        for (int r = 0; r < 4; ++r) {
          const int kt = kt0 + i * 16 + lg * 4 + r;
          pvv[i][r] = (kt <= qg) ? sacc[i][r] : -1e30f;
        }
        pm = fmaxf(pm, fmaxf(fmaxf(pvv[i][0], pvv[i][1]), fmaxf(pvv[i][2], pvv[i][3])));
      }
    } else {
#pragma unroll
      for (int i = 0; i < 4; ++i) {
#pragma unroll
        for (int r = 0; r < 4; ++r) pvv[i][r] = sacc[i][r];
        pm = fmaxf(pm, fmaxf(fmaxf(pvv[i][0], pvv[i][1]), fmaxf(pvv[i][2], pvv[i][3])));
      }
    }

    // defer-max with per-lane vote (mrow row-uniform => vote == reduced check)
    if (!__all(pm <= mrow)) {
      float pmf = fmaxf(pm, __shfl_xor(pm, 16));
      pmf = fmaxf(pmf, __shfl_xor(pmf, 32));     // row-uniform full max
      const float mnew = fmaxf(mrow, pmf);
      const float sc = exp2f(mrow - mnew);
      lsum *= sc;
#pragma unroll
      for (int i = 0; i < 4; ++i) oacc[i] *= sc;
      mrow = mnew;
    }

    float tsum = 0.f;
#pragma unroll
    for (int i = 0; i < 4; ++i) {
      float e0 = exp2f(pvv[i][0] - mrow);
      float e1 = exp2f(pvv[i][1] - mrow);
      float e2 = exp2f(pvv[i][2] - mrow);
      float e3 = exp2f(pvv[i][3] - mrow);
      tsum += (e0 + e1) + (e2 + e3);
      uint2 pk;
      pk.x = cvtpk(e0, e1);
      pk.y = cvtpk(e2, e3);
      // P[lr][i*16+lg*4 ..+4): byte lr*128 + i*32 + lg*8, XOR-swizzled by row
      *(uint2*)(ppb + ((lr * 128 + i * 32 + lg * 8) ^ sw)) = pk;
    }
    lsum += tsum;                       // lane-local partial; reduced once at end

    // O^T += V^T * P^T  (P read with the same row-XOR swizzle)
    __builtin_amdgcn_s_setprio(1);
#pragma unroll
    for (int ks = 0; ks < 2; ++ks) {
      u16x8 pf = *(const u16x8*)(ppb + ((lr * 128 + lg * 16 + ks * 64) ^ sw));
#pragma unroll
      for (int dblk = 0; dblk < 4; ++dblk) {
        const int ro = (dblk * 16 + lr) * 128;
        u16x8 vf = *(const u16x8*)(svc + ro + ((lg * 16 + ks * 64) ^ sw));
        oacc[dblk] = mfma16(vf, pf, oacc[dblk]);
      }
    }
    __builtin_amdgcn_s_setprio(0);

    if (t + 1 < nt) {   // write prefetched tile into alternate buffer
      char* dk = skb[cur ^ 1];
      char* dv = svb[cur ^ 1];
      *(u16x8*)(dk + wo0) = ka; *(u16x8*)(dk + wo1) = kb;
      *(u16x8*)(dv + wo0) = va; *(u16x8*)(dv + wo1) = vb;
    }
    cur ^= 1;
  }

  // final denominator reduction (once per block, not per tile)
  lsum += __shfl_xor(lsum, 16);
  lsum += __shfl_xor(lsum, 32);
  const float inv = 1.0f / lsum;
#pragma unroll
  for (int dblk = 0; dblk < 4; ++dblk) {
    uint2 pk;
    pk.x = cvtpk(oacc[dblk][0] * inv, oacc[dblk][1] * inv);
    pk.y = cvtpk(oacc[dblk][2] * inv, oacc[dblk][3] * inv);
    *(uint2*)&y[(size_t)(qt0 + lr) * C_DIM + h * 64 + dblk * 16 + lg * 4] = pk;
  }
}

extern "C" void kernel_launch(void* const* d_in, const int* in_sizes, int n_in,
                              void* d_out, int out_size, void* d_ws, size_t ws_size,
                              hipStream_t stream) {
  const float* x  = (const float*)d_in[0];
  const float* wq = (const float*)d_in[1];
  const float* bq = (const float*)d_in[2];
  const float* wk = (const float*)d_in[3];
  const float* bk = (const float*)d_in[4];
  const float* wv = (const float*)d_in[5];
  const float* bv = (const float*)d_in[6];
  const float* wp = (const float*)d_in[7];
  const float* bp = (const float*)d_in[8];

  char* ws = (char*)d_ws;
  const size_t MB = 1024 * 1024;
  u16* xb  = (u16*)(ws + 0 * MB);
  u16* wqb = (u16*)(ws + 8 * MB);
  u16* wkb = (u16*)(ws + 10 * MB);
  u16* wvb = (u16*)(ws + 12 * MB);
  u16* wpb = (u16*)(ws + 14 * MB);
  u16* qh  = (u16*)(ws + 16 * MB);
  u16* kh  = (u16*)(ws + 24 * MB);
  u16* vt  = (u16*)(ws + 32 * MB);
  u16* y   = (u16*)(ws + 40 * MB);

  cvt_kernel<<<dim3(2048), dim3(256), 0, stream>>>(x, xb, 524288);
  wcvt_kernel<<<dim3(512, 4), dim3(256), 0, stream>>>(
      wq, wk, wv, wp, wqb, wkb, wvb, wpb, 131072);

  gemm_qkv<<<dim3(32, 8, 3), dim3(256), 0, stream>>>(
      xb, wqb, wkb, wvb, bq, bk, bv, qh, kh, vt);

  attn_kernel<<<dim3(1024), dim3(256), 0, stream>>>(qh, kh, vt, y);

  gemm_proj<<<dim3(32, 8), dim3(256), 0, stream>>>(y, wpb, bp, (float*)d_out);
}

// Round 11
// 147.119 us; speedup vs baseline: 1.3603x; 1.0417x over previous
//
#include <hip/hip_runtime.h>
#include <stdint.h>

#define T_LEN 4096
#define C_DIM 1024
#define NH 16
#define CLOG2E 0.18033688011112042f   // 0.125 * log2(e)

typedef uint16_t u16;
typedef __attribute__((ext_vector_type(4))) float f32x4;
typedef __attribute__((ext_vector_type(8))) __bf16 bf16x8;
typedef __attribute__((ext_vector_type(8))) uint16_t u16x8;
typedef __attribute__((ext_vector_type(4))) float fvec4;

static __device__ __forceinline__ u16 f2b(float f) {
  union { float f; uint32_t u; } v; v.f = f;
  uint32_t u = v.u;
  return (u16)((u + 0x7fffu + ((u >> 16) & 1u)) >> 16);
}

// packed fp32->bf16x2 (RNE) — inline asm, no builtin on gfx950
static __device__ __forceinline__ uint32_t cvtpk(float lo, float hi) {
  uint32_t r;
  asm("v_cvt_pk_bf16_f32 %0, %1, %2" : "=v"(r) : "v"(lo), "v"(hi));
  return r;
}

static __device__ __forceinline__ f32x4 mfma16(u16x8 a, u16x8 b, f32x4 c) {
  return __builtin_amdgcn_mfma_f32_16x16x32_bf16(
      __builtin_bit_cast(bf16x8, a), __builtin_bit_cast(bf16x8, b), c, 0, 0, 0);
}

static __device__ __forceinline__ void gload_lds16(const void* g, void* l) {
  __builtin_amdgcn_global_load_lds(
      (const __attribute__((address_space(1))) uint32_t*)g,
      (__attribute__((address_space(3))) uint32_t*)l, 16, 0, 0);
}

// ---------------- merged fp32 -> bf16 cast (1 launch) ----------------
// grid (512, 8): y=0..3 -> wq,wk,wv,wp (131072 x8 each); y=4..7 -> x quarters.
__global__ void cast_all(const float* __restrict__ x,
                         const float* __restrict__ wq, const float* __restrict__ wk,
                         const float* __restrict__ wv, const float* __restrict__ wp,
                         u16* __restrict__ xb,
                         u16* __restrict__ wqb, u16* __restrict__ wkb,
                         u16* __restrict__ wvb, u16* __restrict__ wpb) {
  int i = blockIdx.x * blockDim.x + threadIdx.x;
  if (i >= 131072) return;
  const int z = blockIdx.y;
  const float* in;
  u16* out;
  if (z < 4) {
    in  = (z == 0) ? wq  : (z == 1) ? wk  : (z == 2) ? wv  : wp;
    out = (z == 0) ? wqb : (z == 1) ? wkb : (z == 2) ? wvb : wpb;
  } else {
    in  = x  + (size_t)(z - 4) * 131072 * 8;
    out = xb + (size_t)(z - 4) * 131072 * 8;
  }
  const fvec4* p = (const fvec4*)(in + (size_t)i * 8);
  fvec4 a = p[0], b = p[1];
  u16x8 o;
  o[0] = f2b(a[0]); o[1] = f2b(a[1]); o[2] = f2b(a[2]); o[3] = f2b(a[3]);
  o[4] = f2b(b[0]); o[5] = f2b(b[1]); o[6] = f2b(b[2]); o[7] = f2b(b[3]);
  *(u16x8*)(out + (size_t)i * 8) = o;
}

// ---------------- QKV GEMM (m97 structure, unchanged) ----------------
// z=0: Q head-major, PRE-SCALED by 0.125*log2e (fp32, exact). z=1: K. z=2: V^T [h][d][t].
__global__ __launch_bounds__(256) void gemm_qkv(
    const u16* __restrict__ xb,
    const u16* __restrict__ wqb, const u16* __restrict__ wkb, const u16* __restrict__ wvb,
    const float* __restrict__ bq, const float* __restrict__ bk, const float* __restrict__ bv,
    u16* __restrict__ qh, u16* __restrict__ kh, u16* __restrict__ vt)
{
  __shared__ u16 sA[128 * 32];
  __shared__ u16 sB[128 * 32];
  const int K = C_DIM;
  const int z = blockIdx.z;
  const u16* wb = (z == 0) ? wqb : (z == 1) ? wkb : wvb;
  const float* bias = (z == 0) ? bq : (z == 1) ? bk : bv;
  const int m0 = blockIdx.x * 128;
  const int n0 = blockIdx.y * 128;
  const int tid = threadIdx.x;
  const int lane = tid & 63;
  const int w = tid >> 6;
  const int wm = (w >> 1) * 64;
  const int wn = (w & 1) * 64;
  const int lr = lane & 15;
  const int lk = (lane >> 4) * 8;

  f32x4 acc[4][4];
#pragma unroll
  for (int m = 0; m < 4; ++m)
#pragma unroll
    for (int n = 0; n < 4; ++n) acc[m][n] = (f32x4){0.f, 0.f, 0.f, 0.f};

  const int srow = tid >> 2;
  const int scol = (tid & 3) * 8;
  const u16* gA = xb + (size_t)(m0 + srow) * K + scol;
  const u16* gB = wb + (size_t)(n0 + srow) * K + scol;

  for (int k0 = 0; k0 < K; k0 += 32) {
    gload_lds16(gA + k0,          &sA[tid * 8]);
    gload_lds16(gA + 64 * K + k0, &sA[2048 + tid * 8]);
    gload_lds16(gB + k0,          &sB[tid * 8]);
    gload_lds16(gB + 64 * K + k0, &sB[2048 + tid * 8]);
    __syncthreads();
    u16x8 af[4], bfr[4];
#pragma unroll
    for (int m = 0; m < 4; ++m) af[m]  = *(const u16x8*)&sA[(wm + m * 16 + lr) * 32 + lk];
#pragma unroll
    for (int n = 0; n < 4; ++n) bfr[n] = *(const u16x8*)&sB[(wn + n * 16 + lr) * 32 + lk];
#pragma unroll
    for (int m = 0; m < 4; ++m)
#pragma unroll
      for (int n = 0; n < 4; ++n) acc[m][n] = mfma16(af[m], bfr[n], acc[m][n]);
    __syncthreads();
  }

  const int lg = lane >> 4;
#pragma unroll
  for (int n = 0; n < 4; ++n) {
    const int o = n0 + wn + n * 16 + lr;
    const float bb = bias[o];
    const int h = o >> 6;
    const int d = o & 63;
#pragma unroll
    for (int m = 0; m < 4; ++m) {
      const int tb = m0 + wm + m * 16 + lg * 4;
      if (z == 2) {
        uint2 pk;
        pk.x = cvtpk(acc[m][n][0] + bb, acc[m][n][1] + bb);
        pk.y = cvtpk(acc[m][n][2] + bb, acc[m][n][3] + bb);
        *(uint2*)&vt[(size_t)o * T_LEN + tb] = pk;
      } else if (z == 0) {
#pragma unroll
        for (int r = 0; r < 4; ++r)
          qh[((size_t)h * T_LEN + tb + r) * 64 + d] = f2b((acc[m][n][r] + bb) * CLOG2E);
      } else {
#pragma unroll
        for (int r = 0; r < 4; ++r)
          kh[((size_t)h * T_LEN + tb + r) * 64 + d] = f2b(acc[m][n][r] + bb);
      }
    }
  }
}

// ---------------- output projection: 128x64 tiles, grid (32,16)=512 -> 2 blocks/CU ----
__global__ __launch_bounds__(256) void gemm_proj(
    const u16* __restrict__ yb, const u16* __restrict__ wpb,
    const float* __restrict__ bp, float* __restrict__ out)
{
  __shared__ u16 sA[128 * 32];
  __shared__ u16 sB[64 * 32];
  const int K = C_DIM;
  const int m0 = blockIdx.x * 128;
  const int n0 = blockIdx.y * 64;
  const int tid = threadIdx.x;
  const int lane = tid & 63;
  const int w = tid >> 6;
  const int wm = w * 32;               // wave owns 32 rows x 64 cols
  const int lr = lane & 15;
  const int lk = (lane >> 4) * 8;

  f32x4 acc[2][4];
#pragma unroll
  for (int m = 0; m < 2; ++m)
#pragma unroll
    for (int n = 0; n < 4; ++n) acc[m][n] = (f32x4){0.f, 0.f, 0.f, 0.f};

  const int srow = tid >> 2;
  const int scol = (tid & 3) * 8;
  const u16* gA = yb  + (size_t)(m0 + srow) * K + scol;
  const u16* gB = wpb + (size_t)(n0 + srow) * K + scol;   // 64 rows of Wp

  for (int k0 = 0; k0 < K; k0 += 32) {
    gload_lds16(gA + k0,          &sA[tid * 8]);
    gload_lds16(gA + 64 * K + k0, &sA[2048 + tid * 8]);
    gload_lds16(gB + k0,          &sB[tid * 8]);          // one load covers 64x32
    __syncthreads();
    u16x8 af[2], bfr[4];
#pragma unroll
    for (int m = 0; m < 2; ++m) af[m]  = *(const u16x8*)&sA[(wm + m * 16 + lr) * 32 + lk];
#pragma unroll
    for (int n = 0; n < 4; ++n) bfr[n] = *(const u16x8*)&sB[(n * 16 + lr) * 32 + lk];
#pragma unroll
    for (int m = 0; m < 2; ++m)
#pragma unroll
      for (int n = 0; n < 4; ++n) acc[m][n] = mfma16(af[m], bfr[n], acc[m][n]);
    __syncthreads();
  }

  const int lg = lane >> 4;
#pragma unroll
  for (int n = 0; n < 4; ++n) {
    const int o = n0 + n * 16 + lr;
    const float bb = bp[o];
#pragma unroll
    for (int m = 0; m < 2; ++m) {
      const int tb = m0 + wm + m * 16 + lg * 4;
#pragma unroll
      for (int r = 0; r < 4; ++r)
        out[(size_t)(tb + r) * C_DIM + o] = acc[m][n][r] + bb;
    }
  }
}

// ---------------- flash attention v11 = R10 + VALU trims ----------------
// Structure identical to R10 (best-known: K+V LDS dbuf + XOR swizzle, swizzled P,
// XCD-chunked LPT grid 1024, per-lane defer-max vote, lane-local lsum, cvt_pk,
// setprio). Trims: mask in place (no pvv copy), max3-fusable max chains,
// 4-way parallel tsum partials.
__global__ __launch_bounds__(256) void attn_kernel(
    const u16* __restrict__ qh, const u16* __restrict__ kh, const u16* __restrict__ vt,
    u16* __restrict__ y)
{
  __shared__ char skb[2][8192];
  __shared__ char svb[2][8192];
  __shared__ u16 pp[4][16][64];        // 8192 B, XOR-swizzled
  const int bid = blockIdx.x;
  const int j = bid >> 3;
  const int h = ((bid & 7) << 1) + (j & 1);
  const int qb = 63 - (j >> 1);
  const int nt = qb + 1;
  const int tid = threadIdx.x;
  const int lane = tid & 63;
  const int w = tid >> 6;
  const int lr = lane & 15;
  const int lg = lane >> 4;
  const int sw = (lr & 7) << 4;
  const int qt0 = qb * 64 + w * 16;

  const int srow = tid >> 2;
  const int scb = (tid & 3) * 32;
  const int wo0 = srow * 128 + (scb ^ ((srow & 7) << 4));
  const int wo1 = srow * 128 + ((scb + 16) ^ ((srow & 7) << 4));
  const u16* gkbase = kh + ((size_t)h * T_LEN + srow) * 64 + (tid & 3) * 16;
  const u16* gvbase = vt + ((size_t)h * 64 + srow) * T_LEN + (tid & 3) * 16;
  char* ppb = (char*)&pp[w][0][0];

  const u16* qbase = qh + ((size_t)h * T_LEN + qt0 + lr) * 64 + lg * 8;
  u16x8 qf0 = *(const u16x8*)(qbase);
  u16x8 qf1 = *(const u16x8*)(qbase + 32);

  f32x4 oacc[4];
#pragma unroll
  for (int i = 0; i < 4; ++i) oacc[i] = (f32x4){0.f, 0.f, 0.f, 0.f};
  float mrow = -1e30f, lsum = 0.f;

  u16x8 ka = *(const u16x8*)(gkbase);
  u16x8 kb = *(const u16x8*)(gkbase + 8);
  u16x8 va = *(const u16x8*)(gvbase);
  u16x8 vb = *(const u16x8*)(gvbase + 8);
  *(u16x8*)(skb[0] + wo0) = ka; *(u16x8*)(skb[0] + wo1) = kb;
  *(u16x8*)(svb[0] + wo0) = va; *(u16x8*)(svb[0] + wo1) = vb;
  int cur = 0;

  for (int t = 0; t < nt; ++t) {
    __syncthreads();   // buffer[cur] writes visible
    if (t + 1 < nt) {
      const size_t ko = (size_t)(t + 1) * 4096;
      ka = *(const u16x8*)(gkbase + ko);
      kb = *(const u16x8*)(gkbase + ko + 8);
      va = *(const u16x8*)(gvbase + (t + 1) * 64);
      vb = *(const u16x8*)(gvbase + (t + 1) * 64 + 8);
    }
    const char* skc = skb[cur];
    const char* svc = svb[cur];

    // S^T = K * Q^T  (scale already folded into Q)
    f32x4 sacc[4];
    __builtin_amdgcn_s_setprio(1);
#pragma unroll
    for (int i = 0; i < 4; ++i) {
      const int ro = (i * 16 + lr) * 128;
      u16x8 a0 = *(const u16x8*)(skc + ro + ((lg * 16) ^ sw));
      u16x8 a1 = *(const u16x8*)(skc + ro + ((lg * 16 + 64) ^ sw));
      f32x4 zz = (f32x4){0.f, 0.f, 0.f, 0.f};
      zz = mfma16(a0, qf0, zz);
      zz = mfma16(a1, qf1, zz);
      sacc[i] = zz;
    }
    __builtin_amdgcn_s_setprio(0);

    // mask IN PLACE on the diagonal tile only
    if (t == nt - 1) {
      const int qg = qt0 + lr;
      const int kt0 = t * 64;
#pragma unroll
      for (int i = 0; i < 4; ++i)
#pragma unroll
        for (int r = 0; r < 4; ++r) {
          const int kt = kt0 + i * 16 + lg * 4 + r;
          sacc[i][r] = (kt <= qg) ? sacc[i][r] : -1e30f;
        }
    }
    // per-lane tile max via max3-fusable chains (5 max3 + 5 max)
    float x0 = fmaxf(fmaxf(sacc[0][0], sacc[0][1]), sacc[0][2]);
    float x1 = fmaxf(fmaxf(sacc[0][3], sacc[1][0]), sacc[1][1]);
    float x2 = fmaxf(fmaxf(sacc[1][2], sacc[1][3]), sacc[2][0]);
    float x3 = fmaxf(fmaxf(sacc[2][1], sacc[2][2]), sacc[2][3]);
    float x4 = fmaxf(fmaxf(sacc[3][0], sacc[3][1]), sacc[3][2]);
    float pm = fmaxf(fmaxf(fmaxf(x0, x1), fmaxf(x2, x3)), fmaxf(x4, sacc[3][3]));

    // defer-max with per-lane vote (mrow row-uniform => vote == reduced check)
    if (!__all(pm <= mrow)) {
      float pmf = fmaxf(pm, __shfl_xor(pm, 16));
      pmf = fmaxf(pmf, __shfl_xor(pmf, 32));
      const float mnew = fmaxf(mrow, pmf);
      const float sc = exp2f(mrow - mnew);
      lsum *= sc;
#pragma unroll
      for (int i = 0; i < 4; ++i) oacc[i] *= sc;
      mrow = mnew;
    }

    // exp + pack; 4 parallel partial sums (shorter dependent chain)
    float t0 = 0.f, t1 = 0.f, t2 = 0.f, t3 = 0.f;
#pragma unroll
    for (int i = 0; i < 4; ++i) {
      float e0 = exp2f(sacc[i][0] - mrow);
      float e1 = exp2f(sacc[i][1] - mrow);
      float e2 = exp2f(sacc[i][2] - mrow);
      float e3 = exp2f(sacc[i][3] - mrow);
      t0 += e0; t1 += e1; t2 += e2; t3 += e3;
      uint2 pk;
      pk.x = cvtpk(e0, e1);
      pk.y = cvtpk(e2, e3);
      *(uint2*)(ppb + ((lr * 128 + i * 32 + lg * 8) ^ sw)) = pk;
    }
    lsum += (t0 + t1) + (t2 + t3);

    // O^T += V^T * P^T
    __builtin_amdgcn_s_setprio(1);
#pragma unroll
    for (int ks = 0; ks < 2; ++ks) {
      u16x8 pf = *(const u16x8*)(ppb + ((lr * 128 + lg * 16 + ks * 64) ^ sw));
#pragma unroll
      for (int dblk = 0; dblk < 4; ++dblk) {
        const int ro = (dblk * 16 + lr) * 128;
        u16x8 vf = *(const u16x8*)(svc + ro + ((lg * 16 + ks * 64) ^ sw));
        oacc[dblk] = mfma16(vf, pf, oacc[dblk]);
      }
    }
    __builtin_amdgcn_s_setprio(0);

    if (t + 1 < nt) {
      char* dk = skb[cur ^ 1];
      char* dv = svb[cur ^ 1];
      *(u16x8*)(dk + wo0) = ka; *(u16x8*)(dk + wo1) = kb;
      *(u16x8*)(dv + wo0) = va; *(u16x8*)(dv + wo1) = vb;
    }
    cur ^= 1;
  }

  lsum += __shfl_xor(lsum, 16);
  lsum += __shfl_xor(lsum, 32);
  const float inv = 1.0f / lsum;
#pragma unroll
  for (int dblk = 0; dblk < 4; ++dblk) {
    uint2 pk;
    pk.x = cvtpk(oacc[dblk][0] * inv, oacc[dblk][1] * inv);
    pk.y = cvtpk(oacc[dblk][2] * inv, oacc[dblk][3] * inv);
    *(uint2*)&y[(size_t)(qt0 + lr) * C_DIM + h * 64 + dblk * 16 + lg * 4] = pk;
  }
}

extern "C" void kernel_launch(void* const* d_in, const int* in_sizes, int n_in,
                              void* d_out, int out_size, void* d_ws, size_t ws_size,
                              hipStream_t stream) {
  const float* x  = (const float*)d_in[0];
  const float* wq = (const float*)d_in[1];
  const float* bq = (const float*)d_in[2];
  const float* wk = (const float*)d_in[3];
  const float* bk = (const float*)d_in[4];
  const float* wv = (const float*)d_in[5];
  const float* bv = (const float*)d_in[6];
  const float* wp = (const float*)d_in[7];
  const float* bp = (const float*)d_in[8];

  char* ws = (char*)d_ws;
  const size_t MB = 1024 * 1024;
  u16* xb  = (u16*)(ws + 0 * MB);
  u16* wqb = (u16*)(ws + 8 * MB);
  u16* wkb = (u16*)(ws + 10 * MB);
  u16* wvb = (u16*)(ws + 12 * MB);
  u16* wpb = (u16*)(ws + 14 * MB);
  u16* qh  = (u16*)(ws + 16 * MB);
  u16* kh  = (u16*)(ws + 24 * MB);
  u16* vt  = (u16*)(ws + 32 * MB);
  u16* y   = (u16*)(ws + 40 * MB);

  cast_all<<<dim3(512, 8), dim3(256), 0, stream>>>(
      x, wq, wk, wv, wp, xb, wqb, wkb, wvb, wpb);

  gemm_qkv<<<dim3(32, 8, 3), dim3(256), 0, stream>>>(
      xb, wqb, wkb, wvb, bq, bk, bv, qh, kh, vt);

  attn_kernel<<<dim3(1024), dim3(256), 0, stream>>>(qh, kh, vt, y);

  gemm_proj<<<dim3(32, 16), dim3(256), 0, stream>>>(y, wpb, bp, (float*)d_out);
}

// Round 12
// 144.131 us; speedup vs baseline: 1.3885x; 1.0207x over previous
//
#include <hip/hip_runtime.h>
#include <stdint.h>

#define T_LEN 4096
#define C_DIM 1024
#define NH 16
#define CLOG2E 0.18033688011112042f   // 0.125 * log2(e)

typedef uint16_t u16;
typedef __attribute__((ext_vector_type(4))) float f32x4;
typedef __attribute__((ext_vector_type(8))) __bf16 bf16x8;
typedef __attribute__((ext_vector_type(8))) uint16_t u16x8;
typedef __attribute__((ext_vector_type(4))) float fvec4;

static __device__ __forceinline__ u16 f2b(float f) {
  union { float f; uint32_t u; } v; v.f = f;
  uint32_t u = v.u;
  return (u16)((u + 0x7fffu + ((u >> 16) & 1u)) >> 16);
}

static __device__ __forceinline__ float b2f(u16 b) {
  union { uint32_t u; float f; } v; v.u = ((uint32_t)b) << 16;
  return v.f;
}

// packed fp32->bf16x2 (RNE) — inline asm, no builtin on gfx950
static __device__ __forceinline__ uint32_t cvtpk(float lo, float hi) {
  uint32_t r;
  asm("v_cvt_pk_bf16_f32 %0, %1, %2" : "=v"(r) : "v"(lo), "v"(hi));
  return r;
}

static __device__ __forceinline__ f32x4 mfma16(u16x8 a, u16x8 b, f32x4 c) {
  return __builtin_amdgcn_mfma_f32_16x16x32_bf16(
      __builtin_bit_cast(bf16x8, a), __builtin_bit_cast(bf16x8, b), c, 0, 0, 0);
}

static __device__ __forceinline__ void gload_lds16(const void* g, void* l) {
  __builtin_amdgcn_global_load_lds(
      (const __attribute__((address_space(1))) uint32_t*)g,
      (__attribute__((address_space(3))) uint32_t*)l, 16, 0, 0);
}

// ---------------- merged fp32 -> bf16 cast (1 launch) ----------------
__global__ void cast_all(const float* __restrict__ x,
                         const float* __restrict__ wq, const float* __restrict__ wk,
                         const float* __restrict__ wv, const float* __restrict__ wp,
                         u16* __restrict__ xb,
                         u16* __restrict__ wqb, u16* __restrict__ wkb,
                         u16* __restrict__ wvb, u16* __restrict__ wpb) {
  int i = blockIdx.x * blockDim.x + threadIdx.x;
  if (i >= 131072) return;
  const int z = blockIdx.y;
  const float* in;
  u16* out;
  if (z < 4) {
    in  = (z == 0) ? wq  : (z == 1) ? wk  : (z == 2) ? wv  : wp;
    out = (z == 0) ? wqb : (z == 1) ? wkb : (z == 2) ? wvb : wpb;
  } else {
    in  = x  + (size_t)(z - 4) * 131072 * 8;
    out = xb + (size_t)(z - 4) * 131072 * 8;
  }
  const fvec4* p = (const fvec4*)(in + (size_t)i * 8);
  fvec4 a = p[0], b = p[1];
  u16x8 o;
  o[0] = f2b(a[0]); o[1] = f2b(a[1]); o[2] = f2b(a[2]); o[3] = f2b(a[3]);
  o[4] = f2b(b[0]); o[5] = f2b(b[1]); o[6] = f2b(b[2]); o[7] = f2b(b[3]);
  *(u16x8*)(out + (size_t)i * 8) = o;
}

// ---------------- QKV GEMM (m97 structure, unchanged) ----------------
__global__ __launch_bounds__(256) void gemm_qkv(
    const u16* __restrict__ xb,
    const u16* __restrict__ wqb, const u16* __restrict__ wkb, const u16* __restrict__ wvb,
    const float* __restrict__ bq, const float* __restrict__ bk, const float* __restrict__ bv,
    u16* __restrict__ qh, u16* __restrict__ kh, u16* __restrict__ vt)
{
  __shared__ u16 sA[128 * 32];
  __shared__ u16 sB[128 * 32];
  const int K = C_DIM;
  const int z = blockIdx.z;
  const u16* wb = (z == 0) ? wqb : (z == 1) ? wkb : wvb;
  const float* bias = (z == 0) ? bq : (z == 1) ? bk : bv;
  const int m0 = blockIdx.x * 128;
  const int n0 = blockIdx.y * 128;
  const int tid = threadIdx.x;
  const int lane = tid & 63;
  const int w = tid >> 6;
  const int wm = (w >> 1) * 64;
  const int wn = (w & 1) * 64;
  const int lr = lane & 15;
  const int lk = (lane >> 4) * 8;

  f32x4 acc[4][4];
#pragma unroll
  for (int m = 0; m < 4; ++m)
#pragma unroll
    for (int n = 0; n < 4; ++n) acc[m][n] = (f32x4){0.f, 0.f, 0.f, 0.f};

  const int srow = tid >> 2;
  const int scol = (tid & 3) * 8;
  const u16* gA = xb + (size_t)(m0 + srow) * K + scol;
  const u16* gB = wb + (size_t)(n0 + srow) * K + scol;

  for (int k0 = 0; k0 < K; k0 += 32) {
    gload_lds16(gA + k0,          &sA[tid * 8]);
    gload_lds16(gA + 64 * K + k0, &sA[2048 + tid * 8]);
    gload_lds16(gB + k0,          &sB[tid * 8]);
    gload_lds16(gB + 64 * K + k0, &sB[2048 + tid * 8]);
    __syncthreads();
    u16x8 af[4], bfr[4];
#pragma unroll
    for (int m = 0; m < 4; ++m) af[m]  = *(const u16x8*)&sA[(wm + m * 16 + lr) * 32 + lk];
#pragma unroll
    for (int n = 0; n < 4; ++n) bfr[n] = *(const u16x8*)&sB[(wn + n * 16 + lr) * 32 + lk];
#pragma unroll
    for (int m = 0; m < 4; ++m)
#pragma unroll
      for (int n = 0; n < 4; ++n) acc[m][n] = mfma16(af[m], bfr[n], acc[m][n]);
    __syncthreads();
  }

  const int lg = lane >> 4;
#pragma unroll
  for (int n = 0; n < 4; ++n) {
    const int o = n0 + wn + n * 16 + lr;
    const float bb = bias[o];
    const int h = o >> 6;
    const int d = o & 63;
#pragma unroll
    for (int m = 0; m < 4; ++m) {
      const int tb = m0 + wm + m * 16 + lg * 4;
      if (z == 2) {
        uint2 pk;
        pk.x = cvtpk(acc[m][n][0] + bb, acc[m][n][1] + bb);
        pk.y = cvtpk(acc[m][n][2] + bb, acc[m][n][3] + bb);
        *(uint2*)&vt[(size_t)o * T_LEN + tb] = pk;
      } else if (z == 0) {
#pragma unroll
        for (int r = 0; r < 4; ++r)
          qh[((size_t)h * T_LEN + tb + r) * 64 + d] = f2b((acc[m][n][r] + bb) * CLOG2E);
      } else {
#pragma unroll
        for (int r = 0; r < 4; ++r)
          kh[((size_t)h * T_LEN + tb + r) * 64 + d] = f2b(acc[m][n][r] + bb);
      }
    }
  }
}

// ---------------- output projection: 128x64 tiles (R11, unchanged) ----------------
__global__ __launch_bounds__(256) void gemm_proj(
    const u16* __restrict__ yb, const u16* __restrict__ wpb,
    const float* __restrict__ bp, float* __restrict__ out)
{
  __shared__ u16 sA[128 * 32];
  __shared__ u16 sB[64 * 32];
  const int K = C_DIM;
  const int m0 = blockIdx.x * 128;
  const int n0 = blockIdx.y * 64;
  const int tid = threadIdx.x;
  const int lane = tid & 63;
  const int w = tid >> 6;
  const int wm = w * 32;
  const int lr = lane & 15;
  const int lk = (lane >> 4) * 8;

  f32x4 acc[2][4];
#pragma unroll
  for (int m = 0; m < 2; ++m)
#pragma unroll
    for (int n = 0; n < 4; ++n) acc[m][n] = (f32x4){0.f, 0.f, 0.f, 0.f};

  const int srow = tid >> 2;
  const int scol = (tid & 3) * 8;
  const u16* gA = yb  + (size_t)(m0 + srow) * K + scol;
  const u16* gB = wpb + (size_t)(n0 + srow) * K + scol;

  for (int k0 = 0; k0 < K; k0 += 32) {
    gload_lds16(gA + k0,          &sA[tid * 8]);
    gload_lds16(gA + 64 * K + k0, &sA[2048 + tid * 8]);
    gload_lds16(gB + k0,          &sB[tid * 8]);
    __syncthreads();
    u16x8 af[2], bfr[4];
#pragma unroll
    for (int m = 0; m < 2; ++m) af[m]  = *(const u16x8*)&sA[(wm + m * 16 + lr) * 32 + lk];
#pragma unroll
    for (int n = 0; n < 4; ++n) bfr[n] = *(const u16x8*)&sB[(n * 16 + lr) * 32 + lk];
#pragma unroll
    for (int m = 0; m < 2; ++m)
#pragma unroll
      for (int n = 0; n < 4; ++n) acc[m][n] = mfma16(af[m], bfr[n], acc[m][n]);
    __syncthreads();
  }

  const int lg = lane >> 4;
#pragma unroll
  for (int n = 0; n < 4; ++n) {
    const int o = n0 + n * 16 + lr;
    const float bb = bp[o];
#pragma unroll
    for (int m = 0; m < 2; ++m) {
      const int tb = m0 + wm + m * 16 + lg * 4;
#pragma unroll
      for (int r = 0; r < 4; ++r)
        out[(size_t)(tb + r) * C_DIM + o] = acc[m][n][r] + bb;
    }
  }
}

// ---------------- flash attention v12: split-K chunks + combine ----------------
// Inner tile loop IDENTICAL to R11. Work split: each (h,qb) with qb>=32 becomes
// two chunks (tiles [0,32) and [32,qb+1)) writing unnormalized partials (O bf16,
// m/l fp32) to scratch; qb<32 single chunk writes y directly. 1536 blocks of
// <=32 units, LPT-ordered, XCD-chunked -> 512 queued behind 1024 resident
// (real dynamic balancing; longest serial chain halved).
__global__ __launch_bounds__(256) void attn_kernel(
    const u16* __restrict__ qh, const u16* __restrict__ kh, const u16* __restrict__ vt,
    u16* __restrict__ y, u16* __restrict__ po, float* __restrict__ pml)
{
  __shared__ char skb[2][8192];
  __shared__ char svb[2][8192];
  __shared__ u16 pp[4][16][64];        // 8192 B, XOR-swizzled
  // bid -> (h, qb, chunk): xcd=bid&7 owns heads {2x, 2x+1}; per-head index i:
  //   i<32          -> qb=32+i, chunk0 (tiles 0..31, no diagonal)
  //   i>=32, even k -> qb=63-k, chunk1 (tiles 32..qb, has diagonal)
  //   i>=32, odd  k -> qb=31-k, single chunk (direct write)
  const int bid = blockIdx.x;
  const int j = bid >> 3;                     // 0..191
  const int h = ((bid & 7) << 1) + (j & 1);
  const int i = j >> 1;                       // 0..95
  int qb, c0;
  if (i < 32) { qb = 32 + i; c0 = 0; }
  else {
    const int k = (i - 32) >> 1;
    if (((i - 32) & 1) == 0) { qb = 63 - k; c0 = 1; }
    else                     { qb = 31 - k; c0 = -1; }
  }
  const int t0 = (c0 == 1) ? 32 : 0;
  const int t1 = (c0 == 0) ? 32 : (qb + 1);
  const bool hasdiag = (c0 != 0);

  const int tid = threadIdx.x;
  const int lane = tid & 63;
  const int w = tid >> 6;
  const int lr = lane & 15;
  const int lg = lane >> 4;
  const int sw = (lr & 7) << 4;
  const int qt0 = qb * 64 + w * 16;

  const int srow = tid >> 2;
  const int scb = (tid & 3) * 32;
  const int wo0 = srow * 128 + (scb ^ ((srow & 7) << 4));
  const int wo1 = srow * 128 + ((scb + 16) ^ ((srow & 7) << 4));
  const u16* gkbase = kh + ((size_t)h * T_LEN + srow) * 64 + (tid & 3) * 16;
  const u16* gvbase = vt + ((size_t)h * 64 + srow) * T_LEN + (tid & 3) * 16;
  char* ppb = (char*)&pp[w][0][0];

  const u16* qbase = qh + ((size_t)h * T_LEN + qt0 + lr) * 64 + lg * 8;
  u16x8 qf0 = *(const u16x8*)(qbase);
  u16x8 qf1 = *(const u16x8*)(qbase + 32);

  f32x4 oacc[4];
#pragma unroll
  for (int i2 = 0; i2 < 4; ++i2) oacc[i2] = (f32x4){0.f, 0.f, 0.f, 0.f};
  float mrow = -1e30f, lsum = 0.f;

  u16x8 ka = *(const u16x8*)(gkbase + (size_t)t0 * 4096);
  u16x8 kb = *(const u16x8*)(gkbase + (size_t)t0 * 4096 + 8);
  u16x8 va = *(const u16x8*)(gvbase + t0 * 64);
  u16x8 vb = *(const u16x8*)(gvbase + t0 * 64 + 8);
  *(u16x8*)(skb[0] + wo0) = ka; *(u16x8*)(skb[0] + wo1) = kb;
  *(u16x8*)(svb[0] + wo0) = va; *(u16x8*)(svb[0] + wo1) = vb;
  int cur = 0;

  for (int t = t0; t < t1; ++t) {
    __syncthreads();   // buffer[cur] writes visible
    if (t + 1 < t1) {
      const size_t ko = (size_t)(t + 1) * 4096;
      ka = *(const u16x8*)(gkbase + ko);
      kb = *(const u16x8*)(gkbase + ko + 8);
      va = *(const u16x8*)(gvbase + (t + 1) * 64);
      vb = *(const u16x8*)(gvbase + (t + 1) * 64 + 8);
    }
    const char* skc = skb[cur];
    const char* svc = svb[cur];

    // S^T = K * Q^T  (scale folded into Q)
    f32x4 sacc[4];
    __builtin_amdgcn_s_setprio(1);
#pragma unroll
    for (int i2 = 0; i2 < 4; ++i2) {
      const int ro = (i2 * 16 + lr) * 128;
      u16x8 a0 = *(const u16x8*)(skc + ro + ((lg * 16) ^ sw));
      u16x8 a1 = *(const u16x8*)(skc + ro + ((lg * 16 + 64) ^ sw));
      f32x4 zz = (f32x4){0.f, 0.f, 0.f, 0.f};
      zz = mfma16(a0, qf0, zz);
      zz = mfma16(a1, qf1, zz);
      sacc[i2] = zz;
    }
    __builtin_amdgcn_s_setprio(0);

    // mask in place on the diagonal tile only
    if (hasdiag && t == qb) {
      const int qg = qt0 + lr;
      const int kt0 = t * 64;
#pragma unroll
      for (int i2 = 0; i2 < 4; ++i2)
#pragma unroll
        for (int r = 0; r < 4; ++r) {
          const int kt = kt0 + i2 * 16 + lg * 4 + r;
          sacc[i2][r] = (kt <= qg) ? sacc[i2][r] : -1e30f;
        }
    }
    float x0 = fmaxf(fmaxf(sacc[0][0], sacc[0][1]), sacc[0][2]);
    float x1 = fmaxf(fmaxf(sacc[0][3], sacc[1][0]), sacc[1][1]);
    float x2 = fmaxf(fmaxf(sacc[1][2], sacc[1][3]), sacc[2][0]);
    float x3 = fmaxf(fmaxf(sacc[2][1], sacc[2][2]), sacc[2][3]);
    float x4 = fmaxf(fmaxf(sacc[3][0], sacc[3][1]), sacc[3][2]);
    float pm = fmaxf(fmaxf(fmaxf(x0, x1), fmaxf(x2, x3)), fmaxf(x4, sacc[3][3]));

    if (!__all(pm <= mrow)) {
      float pmf = fmaxf(pm, __shfl_xor(pm, 16));
      pmf = fmaxf(pmf, __shfl_xor(pmf, 32));
      const float mnew = fmaxf(mrow, pmf);
      const float sc = exp2f(mrow - mnew);
      lsum *= sc;
#pragma unroll
      for (int i2 = 0; i2 < 4; ++i2) oacc[i2] *= sc;
      mrow = mnew;
    }

    float u0 = 0.f, u1 = 0.f, u2 = 0.f, u3 = 0.f;
#pragma unroll
    for (int i2 = 0; i2 < 4; ++i2) {
      float e0 = exp2f(sacc[i2][0] - mrow);
      float e1 = exp2f(sacc[i2][1] - mrow);
      float e2 = exp2f(sacc[i2][2] - mrow);
      float e3 = exp2f(sacc[i2][3] - mrow);
      u0 += e0; u1 += e1; u2 += e2; u3 += e3;
      uint2 pk;
      pk.x = cvtpk(e0, e1);
      pk.y = cvtpk(e2, e3);
      *(uint2*)(ppb + ((lr * 128 + i2 * 32 + lg * 8) ^ sw)) = pk;
    }
    lsum += (u0 + u1) + (u2 + u3);

    __builtin_amdgcn_s_setprio(1);
#pragma unroll
    for (int ks = 0; ks < 2; ++ks) {
      u16x8 pf = *(const u16x8*)(ppb + ((lr * 128 + lg * 16 + ks * 64) ^ sw));
#pragma unroll
      for (int dblk = 0; dblk < 4; ++dblk) {
        const int ro = (dblk * 16 + lr) * 128;
        u16x8 vf = *(const u16x8*)(svc + ro + ((lg * 16 + ks * 64) ^ sw));
        oacc[dblk] = mfma16(vf, pf, oacc[dblk]);
      }
    }
    __builtin_amdgcn_s_setprio(0);

    if (t + 1 < t1) {
      char* dk = skb[cur ^ 1];
      char* dv = svb[cur ^ 1];
      *(u16x8*)(dk + wo0) = ka; *(u16x8*)(dk + wo1) = kb;
      *(u16x8*)(dv + wo0) = va; *(u16x8*)(dv + wo1) = vb;
    }
    cur ^= 1;
  }

  // row-sum reduction (lanes sharing lr cover the row's 64 kt)
  lsum += __shfl_xor(lsum, 16);
  lsum += __shfl_xor(lsum, 32);

  if (c0 < 0) {
    // single chunk: normalized direct write
    const float inv = 1.0f / lsum;
#pragma unroll
    for (int dblk = 0; dblk < 4; ++dblk) {
      uint2 pk;
      pk.x = cvtpk(oacc[dblk][0] * inv, oacc[dblk][1] * inv);
      pk.y = cvtpk(oacc[dblk][2] * inv, oacc[dblk][3] * inv);
      *(uint2*)&y[(size_t)(qt0 + lr) * C_DIM + h * 64 + dblk * 16 + lg * 4] = pk;
    }
  } else {
    // partial: unnormalized O (bf16) + per-row (m, l)
    const int slot = (((h << 5) + (qb - 32)) << 1) + c0;
    u16* pob = po + (size_t)slot * 4096 + (size_t)(w * 16 + lr) * 64;
#pragma unroll
    for (int dblk = 0; dblk < 4; ++dblk) {
      uint2 pk;
      pk.x = cvtpk(oacc[dblk][0], oacc[dblk][1]);
      pk.y = cvtpk(oacc[dblk][2], oacc[dblk][3]);
      *(uint2*)(pob + dblk * 16 + lg * 4) = pk;
    }
    if (lg == 0) {
      float2* pm2 = (float2*)pml;
      pm2[slot * 64 + w * 16 + lr] = make_float2(mrow, lsum);
    }
  }
}

// ---------------- partial combine: 512 blocks (h, qb>=32), 256 thr ----------------
__global__ __launch_bounds__(256) void attn_combine(
    const u16* __restrict__ po, const float* __restrict__ pml, u16* __restrict__ y)
{
  const int bid = blockIdx.x;            // 0..511
  const int h = bid >> 5;
  const int q5 = bid & 31;               // qb - 32
  const int tid = threadIdx.x;
  const int row = tid >> 2;              // 0..63
  const int dseg = (tid & 3) * 16;
  const int slot0 = (((h << 5) + q5) << 1);
  const float2 ml0 = ((const float2*)pml)[slot0 * 64 + row];
  const float2 ml1 = ((const float2*)pml)[(slot0 + 1) * 64 + row];
  const float m = fmaxf(ml0.x, ml1.x);
  const float f0 = exp2f(ml0.x - m);
  const float f1 = exp2f(ml1.x - m);
  const float inv = 1.0f / (ml0.y * f0 + ml1.y * f1);
  const float g0 = f0 * inv, g1 = f1 * inv;
  const u16* p0 = po + (size_t)slot0 * 4096 + row * 64 + dseg;
  const u16* p1 = p0 + 4096;
  u16x8 a0 = *(const u16x8*)(p0);
  u16x8 a1 = *(const u16x8*)(p0 + 8);
  u16x8 b0 = *(const u16x8*)(p1);
  u16x8 b1 = *(const u16x8*)(p1 + 8);
  uint4 o0, o1;
  float r0, r1;
  r0 = b2f(a0[0]) * g0 + b2f(b0[0]) * g1; r1 = b2f(a0[1]) * g0 + b2f(b0[1]) * g1;
  o0.x = cvtpk(r0, r1);
  r0 = b2f(a0[2]) * g0 + b2f(b0[2]) * g1; r1 = b2f(a0[3]) * g0 + b2f(b0[3]) * g1;
  o0.y = cvtpk(r0, r1);
  r0 = b2f(a0[4]) * g0 + b2f(b0[4]) * g1; r1 = b2f(a0[5]) * g0 + b2f(b0[5]) * g1;
  o0.z = cvtpk(r0, r1);
  r0 = b2f(a0[6]) * g0 + b2f(b0[6]) * g1; r1 = b2f(a0[7]) * g0 + b2f(b0[7]) * g1;
  o0.w = cvtpk(r0, r1);
  r0 = b2f(a1[0]) * g0 + b2f(b1[0]) * g1; r1 = b2f(a1[1]) * g0 + b2f(b1[1]) * g1;
  o1.x = cvtpk(r0, r1);
  r0 = b2f(a1[2]) * g0 + b2f(b1[2]) * g1; r1 = b2f(a1[3]) * g0 + b2f(b1[3]) * g1;
  o1.y = cvtpk(r0, r1);
  r0 = b2f(a1[4]) * g0 + b2f(b1[4]) * g1; r1 = b2f(a1[5]) * g0 + b2f(b1[5]) * g1;
  o1.z = cvtpk(r0, r1);
  r0 = b2f(a1[6]) * g0 + b2f(b1[6]) * g1; r1 = b2f(a1[7]) * g0 + b2f(b1[7]) * g1;
  o1.w = cvtpk(r0, r1);
  u16* yp = y + (size_t)((q5 + 32) * 64 + row) * C_DIM + h * 64 + dseg;
  *(uint4*)(yp) = o0;
  *(uint4*)(yp + 8) = o1;
}

extern "C" void kernel_launch(void* const* d_in, const int* in_sizes, int n_in,
                              void* d_out, int out_size, void* d_ws, size_t ws_size,
                              hipStream_t stream) {
  const float* x  = (const float*)d_in[0];
  const float* wq = (const float*)d_in[1];
  const float* bq = (const float*)d_in[2];
  const float* wk = (const float*)d_in[3];
  const float* bk = (const float*)d_in[4];
  const float* wv = (const float*)d_in[5];
  const float* bv = (const float*)d_in[6];
  const float* wp = (const float*)d_in[7];
  const float* bp = (const float*)d_in[8];

  char* ws = (char*)d_ws;
  const size_t MB = 1024 * 1024;
  u16* xb  = (u16*)(ws + 0 * MB);
  u16* wqb = (u16*)(ws + 8 * MB);
  u16* wkb = (u16*)(ws + 10 * MB);
  u16* wvb = (u16*)(ws + 12 * MB);
  u16* wpb = (u16*)(ws + 14 * MB);
  u16* qh  = (u16*)(ws + 16 * MB);
  u16* kh  = (u16*)(ws + 24 * MB);
  u16* vt  = (u16*)(ws + 32 * MB);
  u16* y   = (u16*)(ws + 40 * MB);
  // partial buffers reuse the region dead after gemm_qkv (xb + wqb):
  u16*   po  = (u16*)(ws + 0 * MB);    // 1024 slots x 64 rows x 64 d bf16 = 8 MB
  float* pml = (float*)(ws + 8 * MB);  // 1024 slots x 64 rows x {m,l} f32 = 0.5 MB

  cast_all<<<dim3(512, 8), dim3(256), 0, stream>>>(
      x, wq, wk, wv, wp, xb, wqb, wkb, wvb, wpb);

  gemm_qkv<<<dim3(32, 8, 3), dim3(256), 0, stream>>>(
      xb, wqb, wkb, wvb, bq, bk, bv, qh, kh, vt);

  attn_kernel<<<dim3(1536), dim3(256), 0, stream>>>(qh, kh, vt, y, po, pml);

  attn_combine<<<dim3(512), dim3(256), 0, stream>>>(po, pml, y);

  gemm_proj<<<dim3(32, 16), dim3(256), 0, stream>>>(y, wpb, bp, (float*)d_out);
}